// Round 1
// baseline (529.493 us; speedup 1.0000x reference)
//
#include <hip/hip_runtime.h>
#include <math.h>

// GAT structural encoder: out = x + h1 + h2
//   h1 = relu(gat(x;  W1,a_src1,a_dst1,b1))
//   h2 = relu(gat(h1; W2,a_src2,a_dst2,b2))
// gat: h = X@W; e = lrelu(asrc[row]+adst[col]); softmax over incoming edges of col;
//      out[n] = sum alpha * h[row] + b   (self-loops added)
// Strategy: build CSR by destination once per launch (no f32 atomics anywhere);
// one wave per destination node accumulates weighted sum + weight sum in regs.

constexpr int D = 128;
constexpr int H8 = 8;

static __device__ __forceinline__ float lrelu(float v) {
  return v > 0.f ? v : 0.2f * v;
}

// ---------------- CSR build ----------------
__global__ void zero_int_kernel(int* __restrict__ p, int n) {
  int i = blockIdx.x * blockDim.x + threadIdx.x;
  if (i < n) p[i] = 0;
}

__global__ void deg_kernel(const int* __restrict__ col, int* __restrict__ deg, int E) {
  int e = blockIdx.x * blockDim.x + threadIdx.x;
  if (e < E) atomicAdd(&deg[col[e]], 1);
}

// single-block exclusive scan over n ints (n ~ 50000), off[n] = total
__global__ __launch_bounds__(1024) void scan_kernel(const int* __restrict__ deg,
                                                    int* __restrict__ off, int n) {
  __shared__ int wsum[16];
  __shared__ int running_s;
  int tid = threadIdx.x, lane = tid & 63, w = tid >> 6;
  if (tid == 0) running_s = 0;
  __syncthreads();
  for (int base = 0; base < n; base += 1024) {
    int i = base + tid;
    int v = (i < n) ? deg[i] : 0;
    int s = v;
    #pragma unroll
    for (int d_ = 1; d_ < 64; d_ <<= 1) {
      int t = __shfl_up(s, d_);
      if (lane >= d_) s += t;
    }
    if (lane == 63) wsum[w] = s;
    __syncthreads();
    if (w == 0 && lane < 16) {
      int xv = wsum[lane];
      #pragma unroll
      for (int d_ = 1; d_ < 16; d_ <<= 1) {
        int t = __shfl_up(xv, d_);
        if (lane >= d_) xv += t;
      }
      wsum[lane] = xv;  // inclusive scan of wave sums
    }
    __syncthreads();
    int waveoff = (w == 0) ? 0 : wsum[w - 1];
    if (i < n) off[i] = running_s + waveoff + s - v;  // exclusive
    __syncthreads();
    if (tid == 1023) running_s += wsum[15];
    __syncthreads();
  }
  if (tid == 0) off[n] = running_s;
}

__global__ void scatter_kernel(const int* __restrict__ row, const int* __restrict__ col,
                               const int* __restrict__ off, int* __restrict__ cur,
                               int* __restrict__ csr_src, int E) {
  int e = blockIdx.x * blockDim.x + threadIdx.x;
  if (e < E) {
    int c = col[e];
    int p = atomicAdd(&cur[c], 1);
    csr_src[off[c] + p] = row[e];
  }
}

// ---------------- dense: Hf = X @ W  (f32, W-half in LDS) ----------------
__global__ __launch_bounds__(256) void gemm_kernel(const float* __restrict__ X,
                                                   const float* __restrict__ W,
                                                   float* __restrict__ Hf, int n) {
  __shared__ float Wl[128][64];   // 32 KB: one 64-col half of W
  __shared__ float Xl[16][132];   // padded: avoid 4-way bank conflict on broadcast col
  int tid = threadIdx.x;
  int chalf = blockIdx.y;  // 0 or 1
  for (int i = tid; i < 128 * 16; i += 256) {  // 2048 float4
    int r = i >> 4, c4 = i & 15;
    *(float4*)&Wl[r][c4 * 4] = *(const float4*)&W[r * 128 + chalf * 64 + c4 * 4];
  }
  int row0 = blockIdx.x * 64;
  int cg = tid & 15;   // 4 cols each -> 64 cols
  int rg = tid >> 4;   // 16 rows per pass
  for (int pass = 0; pass < 4; ++pass) {
    int rbase = row0 + pass * 16;
    __syncthreads();  // Wl ready (pass0) / previous pass done reading Xl
    for (int i = tid; i < 512; i += 256) {  // 16 rows x 32 float4
      int r = i >> 5, c4 = i & 31;
      int gr = rbase + r;
      float4 xv = (gr < n) ? *(const float4*)&X[gr * 128 + c4 * 4]
                           : make_float4(0.f, 0.f, 0.f, 0.f);
      *(float4*)&Xl[r][c4 * 4] = xv;
    }
    __syncthreads();
    float acc0 = 0.f, acc1 = 0.f, acc2 = 0.f, acc3 = 0.f;
    #pragma unroll 4
    for (int k = 0; k < 128; ++k) {
      float xv = Xl[rg][k];
      float4 wv = *(const float4*)&Wl[k][cg * 4];
      acc0 += xv * wv.x; acc1 += xv * wv.y; acc2 += xv * wv.z; acc3 += xv * wv.w;
    }
    int gr = rbase + rg;
    if (gr < n)
      *(float4*)&Hf[gr * 128 + chalf * 64 + cg * 4] = make_float4(acc0, acc1, acc2, acc3);
  }
}

// ---------------- per-(node,head) attention logits ----------------
__global__ void alpha_kernel(const float* __restrict__ Hf, const float* __restrict__ a_src,
                             const float* __restrict__ a_dst, float* __restrict__ asrc,
                             float* __restrict__ adst, int n) {
  int idx = blockIdx.x * blockDim.x + threadIdx.x;
  if (idx >= n * H8) return;
  int h = idx & 7;
  int node = idx >> 3;
  const float4* hv = (const float4*)&Hf[node * D + h * 16];
  const float4* av = (const float4*)&a_src[h * 16];
  const float4* bv = (const float4*)&a_dst[h * 16];
  float s = 0.f, d = 0.f;
  #pragma unroll
  for (int j = 0; j < 4; ++j) {
    float4 x4 = hv[j], a4 = av[j], b4 = bv[j];
    s += x4.x * a4.x + x4.y * a4.y + x4.z * a4.z + x4.w * a4.w;
    d += x4.x * b4.x + x4.y * b4.y + x4.z * b4.z + x4.w * b4.w;
  }
  asrc[idx] = s;
  adst[idx] = d;
}

// ---------------- aggregation: one wave per destination node ----------------
// lane l owns channels 2l,2l+1 (head h = l>>3). Accumulate sum(w*feat), sum(w)
// in registers; softmax denominator division at the end. Self-loop folded in.
template <int LAYER>
__global__ __launch_bounds__(256) void aggregate_kernel(
    const float* __restrict__ Hf, const float* __restrict__ asrc,
    const float* __restrict__ adst, const int* __restrict__ off,
    const int* __restrict__ csr_src, const float* __restrict__ bias,
    const float* __restrict__ xin, const float* __restrict__ h1in,
    float* __restrict__ outp, int n) {
  int wid = (blockIdx.x * blockDim.x + threadIdx.x) >> 6;
  int lane = threadIdx.x & 63;
  if (wid >= n) return;
  int dst = wid;
  int h = lane >> 3;
  int d0 = lane * 2;
  float adst_h = adst[dst * 8 + h];
  // self loop (row = col = dst)
  float w = expf(lrelu(asrc[dst * 8 + h] + adst_h));
  float2 f = *(const float2*)&Hf[dst * D + d0];
  float accx = w * f.x, accy = w * f.y;
  float wsum = w;
  int s = off[dst], e = off[dst + 1];
  for (int i = s; i < e; ++i) {
    int src = csr_src[i];
    float we = expf(lrelu(asrc[src * 8 + h] + adst_h));
    float2 fv = *(const float2*)&Hf[src * D + d0];
    accx += we * fv.x;
    accy += we * fv.y;
    wsum += we;
  }
  float inv = 1.f / (wsum + 1e-16f);
  float2 bv = *(const float2*)&bias[d0];
  float r0 = fmaxf(accx * inv + bv.x, 0.f);
  float r1 = fmaxf(accy * inv + bv.y, 0.f);
  if (LAYER == 1) {
    *(float2*)&outp[dst * D + d0] = make_float2(r0, r1);
  } else {
    float2 xv = *(const float2*)&xin[dst * D + d0];
    float2 hv = *(const float2*)&h1in[dst * D + d0];
    *(float2*)&outp[dst * D + d0] = make_float2(xv.x + hv.x + r0, xv.y + hv.y + r1);
  }
}

extern "C" void kernel_launch(void* const* d_in, const int* in_sizes, int n_in,
                              void* d_out, int out_size, void* d_ws, size_t ws_size,
                              hipStream_t stream) {
  const float* x = (const float*)d_in[0];
  const int* ei = (const int*)d_in[1];
  const float* W1 = (const float*)d_in[3];
  const float* as1 = (const float*)d_in[4];
  const float* ad1 = (const float*)d_in[5];
  const float* b1 = (const float*)d_in[6];
  const float* W2 = (const float*)d_in[7];
  const float* as2 = (const float*)d_in[8];
  const float* ad2 = (const float*)d_in[9];
  const float* b2 = (const float*)d_in[10];
  float* out = (float*)d_out;

  const int N = in_sizes[0] / D;
  const int E = in_sizes[1] / 2;
  const int* row = ei;
  const int* col = ei + E;

  char* base = (char*)d_ws;
  size_t o = 0;
  auto alloc = [&](size_t bytes) {
    void* p = base + o;
    o = (o + bytes + 255) & ~(size_t)255;
    return p;
  };
  int* deg = (int*)alloc((size_t)N * 4);
  int* cur = (int*)alloc((size_t)N * 4);
  int* off = (int*)alloc((size_t)(N + 1) * 4);
  int* csr_src = (int*)alloc((size_t)E * 4);
  float* hf = (float*)alloc((size_t)N * D * 4);
  float* h1 = (float*)alloc((size_t)N * D * 4);
  float* asrcb = (float*)alloc((size_t)N * H8 * 4);
  float* adstb = (float*)alloc((size_t)N * H8 * 4);
  // total ~58.2 MB of d_ws

  // ---- CSR by destination (shared by both layers) ----
  zero_int_kernel<<<(N + 255) / 256, 256, 0, stream>>>(deg, N);
  zero_int_kernel<<<(N + 255) / 256, 256, 0, stream>>>(cur, N);
  deg_kernel<<<(E + 255) / 256, 256, 0, stream>>>(col, deg, E);
  scan_kernel<<<1, 1024, 0, stream>>>(deg, off, N);
  scatter_kernel<<<(E + 255) / 256, 256, 0, stream>>>(row, col, off, cur, csr_src, E);

  dim3 ggrid((N + 63) / 64, 2);
  // ---- layer 1 ----
  gemm_kernel<<<ggrid, 256, 0, stream>>>(x, W1, hf, N);
  alpha_kernel<<<(N * H8 + 255) / 256, 256, 0, stream>>>(hf, as1, ad1, asrcb, adstb, N);
  aggregate_kernel<1><<<(N + 3) / 4, 256, 0, stream>>>(hf, asrcb, adstb, off, csr_src,
                                                       b1, nullptr, nullptr, h1, N);
  // ---- layer 2 ----
  gemm_kernel<<<ggrid, 256, 0, stream>>>(h1, W2, hf, N);
  alpha_kernel<<<(N * H8 + 255) / 256, 256, 0, stream>>>(hf, as2, ad2, asrcb, adstb, N);
  aggregate_kernel<2><<<(N + 3) / 4, 256, 0, stream>>>(hf, asrcb, adstb, off, csr_src,
                                                       b2, x, h1, out, N);
}